// Round 17
// baseline (85.617 us; speedup 1.0000x reference)
//
#include <hip/hip_runtime.h>
#include <hip/hip_fp16.h>

#define B_SZ 8
#define N_SZ 65536
#define C_SZ 128
#define K_SZ 15
#define THREADS 256
#define S_SPANS 128                   // n-spans per batch (one block each)
#define NSPAN 512                     // n per block
#define WAVE_N 128                    // n per wave
#define MSTEPS (WAVE_N / 32)          // 4 mfma steps per wave
#define NBLKS (B_SZ * S_SPANS)        // 1024
#define TILE_F (16 * C_SZ)            // 2048 floats per block partial (k padded 16)
#define SG 8                          // sumA groups per batch
#define SLOT_PER_SG (S_SPANS / SG)    // 16
#define INV_KP_EXTENT (1.0f / 0.48f)

typedef _Float16 half8_t __attribute__((ext_vector_type(8)));
typedef __fp16 fp16x2_t __attribute__((ext_vector_type(2)));
typedef float float4_t __attribute__((ext_vector_type(4)));

// ---------- fused main: inline per-lane A-frag weight compute + MFMA ----------
// Lane(16q+r): A-frag = w[k=r][n0+8q..+8] computed inline (each (k,n) weight is
// needed by exactly ONE lane -> weights never touch memory).
// B-frag: x[c=r+16ct][n0+8q..+8] via 2 float4 + cvt_pkrtz.
// D: lane(16q+r) reg j = wf[k=4q+j][c=16ct+r]  (layout verified rounds 14-16).
__global__ __launch_bounds__(THREADS, 2) void kpconv_fused(
    const float* __restrict__ p, const float* __restrict__ x,
    const float* __restrict__ kp, float* __restrict__ part2) {
  __shared__ float red[4 * TILE_F];   // 32 KB

  const int tid = threadIdx.x;
  const int bs = blockIdx.x;          // b * S_SPANS + s
  const int b = bs / S_SPANS;
  const int s = bs % S_SPANS;
  const int lane = tid & 63;
  const int wid = tid >> 6;
  const int q = lane >> 4;
  const int r = lane & 15;

  const int n0 = s * NSPAN + wid * WAVE_N + q * 8;
  const float* xl = x + (size_t)b * (C_SZ * N_SZ) + (size_t)r * N_SZ + n0;
  const float* pl = p + ((size_t)b * N_SZ + n0) * 3;

  const int kr = (r < K_SZ) ? r : 0;
  const float kpx = kp[kr * 3 + 0];
  const float kpy = kp[kr * 3 + 1];
  const float kpz = kp[kr * 3 + 2];
  const float kw  = (r < K_SZ) ? 1.0f : 0.0f;   // pad row -> w == 0

  float4_t acc[8];
#pragma unroll
  for (int ct = 0; ct < 8; ++ct)
#pragma unroll
    for (int j = 0; j < 4; ++j) acc[ct][j] = 0.0f;

#pragma unroll 1
  for (int t = 0; t < MSTEPS; ++t) {
    const float* pt = pl + (size_t)t * 32 * 3;
    float wv[8];
#pragma unroll
    for (int i = 0; i < 8; ++i) {
      const float px = pt[3 * i + 0];
      const float py = pt[3 * i + 1];
      const float pz = pt[3 * i + 2];
      const float dx = px - kpx, dy = py - kpy, dz = pz - kpz;
      const float d = sqrtf(fmaf(dx, dx, fmaf(dy, dy, dz * dz)));
      wv[i] = fmaxf(kw - d * INV_KP_EXTENT, 0.0f);
    }
    union { half8_t v; fp16x2_t h[4]; } aa;
    aa.h[0] = __builtin_amdgcn_cvt_pkrtz(wv[0], wv[1]);
    aa.h[1] = __builtin_amdgcn_cvt_pkrtz(wv[2], wv[3]);
    aa.h[2] = __builtin_amdgcn_cvt_pkrtz(wv[4], wv[5]);
    aa.h[3] = __builtin_amdgcn_cvt_pkrtz(wv[6], wv[7]);

#pragma unroll
    for (int ct = 0; ct < 8; ++ct) {
      const float* xp = xl + (size_t)ct * 16 * N_SZ + t * 32;
      const float4_t x0 = *reinterpret_cast<const float4_t*>(xp);
      const float4_t x1 = *reinterpret_cast<const float4_t*>(xp + 4);
      union { half8_t v; fp16x2_t h[4]; } bb;
      bb.h[0] = __builtin_amdgcn_cvt_pkrtz(x0[0], x0[1]);
      bb.h[1] = __builtin_amdgcn_cvt_pkrtz(x0[2], x0[3]);
      bb.h[2] = __builtin_amdgcn_cvt_pkrtz(x1[0], x1[1]);
      bb.h[3] = __builtin_amdgcn_cvt_pkrtz(x1[2], x1[3]);
      acc[ct] = __builtin_amdgcn_mfma_f32_16x16x32_f16(aa.v, bb.v, acc[ct], 0, 0, 0);
    }
  }

  // 4-wave LDS reduce -> part2[bs][2048]
#pragma unroll
  for (int ct = 0; ct < 8; ++ct)
#pragma unroll
    for (int j = 0; j < 4; ++j)
      red[wid * TILE_F + (q * 4 + j) * C_SZ + ct * 16 + r] = acc[ct][j];
  __syncthreads();

  float* pp = part2 + (size_t)bs * TILE_F;
  for (int i = tid; i < TILE_F; i += THREADS)
    pp[i] = (red[i] + red[TILE_F + i]) + (red[2 * TILE_F + i] + red[3 * TILE_F + i]);
}

// ---------- stage A: fold 16 block tiles -> part3[b][SG][2048], coalesced ------
__global__ __launch_bounds__(THREADS) void kpconv_sumA(
    const float* __restrict__ part2, float* __restrict__ part3) {
  const int sg = blockIdx.x;   // 0..SG-1
  const int b  = blockIdx.y;   // 0..7
  const int tid = threadIdx.x;
  const size_t ebase = (size_t)tid * 8;

  const float* src = part2 + ((size_t)b * S_SPANS + sg * SLOT_PER_SG) * TILE_F + ebase;
  float4_t s0 = {0.f, 0.f, 0.f, 0.f}, s1 = {0.f, 0.f, 0.f, 0.f};
#pragma unroll
  for (int j = 0; j < SLOT_PER_SG; ++j) {
    s0 += *reinterpret_cast<const float4_t*>(src + (size_t)j * TILE_F);
    s1 += *reinterpret_cast<const float4_t*>(src + (size_t)j * TILE_F + 4);
  }
  float* dst = part3 + ((size_t)b * SG + sg) * TILE_F + ebase;
  *reinterpret_cast<float4_t*>(dst)     = s0;
  *reinterpret_cast<float4_t*>(dst + 4) = s1;
}

// ---------- final: reduce SG groups + full per-b GEMM, direct store ------------
// One block per b. Phase 1: wf[k][c] = sum_sg part3 -> LDS. Phase 2: 256 thr =
// 128 co x 2 k-halves; out[b][co] = sum_k sum_c wf[k][c] * W[k][c][co].
// Overwrites all of out -> no memset, no atomics.
__global__ __launch_bounds__(THREADS) void kpconv_final(
    const float* __restrict__ part3, const float* __restrict__ W,
    float* __restrict__ out) {
  __shared__ float wf[TILE_F];        // 8 KB (k padded 16 x 128 c)
  __shared__ float ored[C_SZ];
  const int b = blockIdx.x;
  const int tid = threadIdx.x;

  // phase 1: 2048 floats, thread i sums 8 floats over 8 groups (coalesced)
  {
    const float* src = part3 + (size_t)b * SG * TILE_F + (size_t)tid * 8;
    float4_t s0 = {0.f, 0.f, 0.f, 0.f}, s1 = {0.f, 0.f, 0.f, 0.f};
#pragma unroll
    for (int sg = 0; sg < SG; ++sg) {
      s0 += *reinterpret_cast<const float4_t*>(src + (size_t)sg * TILE_F);
      s1 += *reinterpret_cast<const float4_t*>(src + (size_t)sg * TILE_F + 4);
    }
    *reinterpret_cast<float4_t*>(&wf[tid * 8])     = s0;
    *reinterpret_cast<float4_t*>(&wf[tid * 8 + 4]) = s1;
  }
  __syncthreads();

  // phase 2: co = tid&127, kh = tid>>7 handles k in {kh, kh+2, ...}
  const int co = tid & 127;
  const int kh = tid >> 7;
  float acc = 0.0f;
  for (int k = kh; k < K_SZ; k += 2) {
    const float* Wk = W + ((size_t)k * C_SZ) * C_SZ + co;
    const float* wfk = &wf[k * C_SZ];
#pragma unroll 8
    for (int c = 0; c < C_SZ; ++c)
      acc = fmaf(wfk[c], Wk[(size_t)c * C_SZ], acc);
  }
  if (kh == 1) ored[co] = acc;
  __syncthreads();
  if (kh == 0) out[b * C_SZ + co] = acc + ored[co];
}

// ---------- fallback (ws too small): round-12 proven VALU path ----------------
#define FB_ROWS 4
#define FB_G 8
#define FB_NPL 4
#define FB_WSTEP 256
#define FB_NSPAN 2048
#define FB_SPANS 32
#define FB_STEPS 8
#define FB_PART (16 * K_SZ)
#define FB_NBLKS (B_SZ * FB_SPANS * FB_G)

__global__ __launch_bounds__(THREADS, 2) void kpconv_main_fb(
    const float* __restrict__ p, const float* __restrict__ x,
    const float* __restrict__ kp, float* __restrict__ part) {
  __shared__ float kps[K_SZ * 3];
  const int tid = threadIdx.x;
  if (tid < K_SZ * 3) kps[tid] = kp[tid];
  __syncthreads();

  const int blk = blockIdx.x;
  const int cg = blk % FB_G;
  const int bs = blk / FB_G;
  const int b  = bs / FB_SPANS;
  const int s  = bs % FB_SPANS;
  const int lane = tid & 63;
  const int wid  = tid >> 6;

  const float* xl = x + (size_t)b * C_SZ * N_SZ
                  + (size_t)(cg * 16 + wid * FB_ROWS) * N_SZ
                  + s * FB_NSPAN + FB_NPL * lane;
  const float* pb = p + ((size_t)b * N_SZ + s * FB_NSPAN) * 3;

  float acc[FB_ROWS][K_SZ];
#pragma unroll
  for (int r = 0; r < FB_ROWS; ++r)
#pragma unroll
    for (int k = 0; k < K_SZ; ++k) acc[r][k] = 0.0f;

  for (int t = 0; t < FB_STEPS; ++t) {
    float4 xv[FB_ROWS];
#pragma unroll
    for (int r = 0; r < FB_ROWS; ++r)
      xv[r] = *reinterpret_cast<const float4*>(xl + (size_t)r * N_SZ + t * FB_WSTEP);
    const int n0 = t * FB_WSTEP + FB_NPL * lane;
    float w4[4][K_SZ];
#pragma unroll
    for (int j = 0; j < 4; ++j) {
      const float px = pb[3 * (n0 + j) + 0];
      const float py = pb[3 * (n0 + j) + 1];
      const float pz = pb[3 * (n0 + j) + 2];
#pragma unroll
      for (int k = 0; k < K_SZ; ++k) {
        const float dx = px - kps[3 * k + 0];
        const float dy = py - kps[3 * k + 1];
        const float dz = pz - kps[3 * k + 2];
        const float d = sqrtf(fmaf(dx, dx, fmaf(dy, dy, dz * dz)));
        w4[j][k] = fmaxf(1.0f - d * INV_KP_EXTENT, 0.0f);
      }
    }
#pragma unroll
    for (int k = 0; k < K_SZ; ++k)
#pragma unroll
      for (int r = 0; r < FB_ROWS; ++r)
        acc[r][k] = fmaf(w4[0][k], xv[r].x,
                    fmaf(w4[1][k], xv[r].y,
                    fmaf(w4[2][k], xv[r].z,
                    fmaf(w4[3][k], xv[r].w, acc[r][k]))));
  }

  float* pout = part + (size_t)blk * FB_PART + wid * (FB_ROWS * K_SZ);
#pragma unroll
  for (int r = 0; r < FB_ROWS; ++r) {
    float keep = 0.0f;
#pragma unroll
    for (int k = 0; k < K_SZ; ++k) {
      float v = acc[r][k];
      v += __shfl_xor(v, 1);
      v += __shfl_xor(v, 2);
      v += __shfl_xor(v, 4);
      v += __shfl_xor(v, 8);
      v += __shfl_xor(v, 16);
      v += __shfl_xor(v, 32);
      if (lane == k) keep = v;
    }
    if (lane < K_SZ) pout[r * K_SZ + lane] = keep;
  }
}

__global__ __launch_bounds__(C_SZ) void kpconv_reduce_fb(
    const float* __restrict__ part, const float* __restrict__ W,
    float* __restrict__ out) {
  const int k = blockIdx.x;
  const int b = blockIdx.y;
  const int tid = threadIdx.x;
  __shared__ float row[C_SZ];

  const int cg = tid >> 4, wid = (tid >> 2) & 3, r = tid & 3;
  const size_t base = ((size_t)(b * FB_SPANS) * FB_G + cg) * FB_PART
                    + wid * (FB_ROWS * K_SZ) + r * K_SZ + k;
  float sum = 0.0f;
  for (int ss = 0; ss < FB_SPANS; ++ss)
    sum += part[base + (size_t)ss * FB_G * FB_PART];
  row[tid] = sum;
  __syncthreads();

  float acc = 0.0f;
  const float* Wk = W + (size_t)k * C_SZ * C_SZ;
#pragma unroll 8
  for (int c = 0; c < C_SZ; ++c) acc += row[c] * Wk[(size_t)c * C_SZ + tid];
  atomicAdd(&out[b * C_SZ + tid], acc);
}

extern "C" void kernel_launch(void* const* d_in, const int* in_sizes, int n_in,
                              void* d_out, int out_size, void* d_ws, size_t ws_size,
                              hipStream_t stream) {
  const float* p  = (const float*)d_in[0];
  const float* x  = (const float*)d_in[1];
  const float* w  = (const float*)d_in[2];
  const float* kp = (const float*)d_in[3];
  float* out  = (float*)d_out;

  const size_t p2_bytes = (size_t)NBLKS * TILE_F * sizeof(float);        // 8.39 MB
  const size_t p2a = (p2_bytes + 255) & ~(size_t)255;
  const size_t p3_bytes = (size_t)B_SZ * SG * TILE_F * sizeof(float);    // 0.52 MB
  const size_t p3a = (p3_bytes + 255) & ~(size_t)255;

  if (ws_size >= p2a + p3a) {
    float* part2 = (float*)d_ws;
    float* part3 = (float*)((char*)d_ws + p2a);
    kpconv_fused<<<dim3(NBLKS), THREADS, 0, stream>>>(p, x, kp, part2);
    kpconv_sumA<<<dim3(SG, B_SZ), THREADS, 0, stream>>>(part2, part3);
    kpconv_final<<<dim3(B_SZ), THREADS, 0, stream>>>(part3, w, out);
  } else {
    float* part = (float*)d_ws;
    (void)hipMemsetAsync(d_out, 0, (size_t)out_size * sizeof(float), stream);
    kpconv_main_fb<<<dim3(FB_NBLKS), THREADS, 0, stream>>>(p, x, kp, part);
    kpconv_reduce_fb<<<dim3(K_SZ, B_SZ), C_SZ, 0, stream>>>(part, w, out);
  }
}

// Round 18
// 59.629 us; speedup vs baseline: 1.4358x; 1.4358x over previous
//
#include <hip/hip_runtime.h>
#include <hip/hip_fp16.h>

#define B_SZ 8
#define N_SZ 65536
#define C_SZ 128
#define K_SZ 15
#define THREADS 256
#define S_SPANS 128                   // n-spans per batch (one block each)
#define NSPAN 512                     // n per block
#define WAVE_N 128                    // n per wave
#define MSTEPS (WAVE_N / 32)          // 4 mfma steps per wave
#define NBLKS (B_SZ * S_SPANS)        // 1024
#define TILE_F (16 * C_SZ)            // 2048 floats per block partial (k padded 16)
#define SG 8                          // sumA groups per batch
#define SLOT_PER_SG (S_SPANS / SG)    // 16
#define INV_KP_EXTENT (1.0f / 0.48f)

typedef _Float16 half8_t __attribute__((ext_vector_type(8)));
typedef __fp16 fp16x2_t __attribute__((ext_vector_type(2)));
typedef float float4_t __attribute__((ext_vector_type(4)));

// ---------- fused main: inline per-lane A-frag weight compute + MFMA ----------
// Lane(16q+r): A-frag = w[k=r][n0+8q..+8] computed inline (each (k,n) weight is
// needed by exactly ONE lane -> weights never touch memory).
// B-frag: x[c=r+16ct][n0+8q..+8] via 2 float4 + cvt_pkrtz.
// D: lane(16q+r) reg j = wf[k=4q+j][c=16ct+r]  (layout verified rounds 14-16).
__global__ __launch_bounds__(THREADS, 2) void kpconv_fused(
    const float* __restrict__ p, const float* __restrict__ x,
    const float* __restrict__ kp, float* __restrict__ part2) {
  __shared__ float red[4 * TILE_F];   // 32 KB

  const int tid = threadIdx.x;
  const int bs = blockIdx.x;          // b * S_SPANS + s
  const int b = bs / S_SPANS;
  const int s = bs % S_SPANS;
  const int lane = tid & 63;
  const int wid = tid >> 6;
  const int q = lane >> 4;
  const int r = lane & 15;

  const int n0 = s * NSPAN + wid * WAVE_N + q * 8;
  const float* xl = x + (size_t)b * (C_SZ * N_SZ) + (size_t)r * N_SZ + n0;
  const float* pl = p + ((size_t)b * N_SZ + n0) * 3;

  const int kr = (r < K_SZ) ? r : 0;
  const float kpx = kp[kr * 3 + 0];
  const float kpy = kp[kr * 3 + 1];
  const float kpz = kp[kr * 3 + 2];
  const float kw  = (r < K_SZ) ? 1.0f : 0.0f;   // pad row -> w == 0

  float4_t acc[8];
#pragma unroll
  for (int ct = 0; ct < 8; ++ct)
#pragma unroll
    for (int j = 0; j < 4; ++j) acc[ct][j] = 0.0f;

#pragma unroll 1
  for (int t = 0; t < MSTEPS; ++t) {
    const float* pt = pl + (size_t)t * 32 * 3;
    float wv[8];
#pragma unroll
    for (int i = 0; i < 8; ++i) {
      const float px = pt[3 * i + 0];
      const float py = pt[3 * i + 1];
      const float pz = pt[3 * i + 2];
      const float dx = px - kpx, dy = py - kpy, dz = pz - kpz;
      const float d = sqrtf(fmaf(dx, dx, fmaf(dy, dy, dz * dz)));
      wv[i] = fmaxf(kw - d * INV_KP_EXTENT, 0.0f);
    }
    union { half8_t v; fp16x2_t h[4]; } aa;
    aa.h[0] = __builtin_amdgcn_cvt_pkrtz(wv[0], wv[1]);
    aa.h[1] = __builtin_amdgcn_cvt_pkrtz(wv[2], wv[3]);
    aa.h[2] = __builtin_amdgcn_cvt_pkrtz(wv[4], wv[5]);
    aa.h[3] = __builtin_amdgcn_cvt_pkrtz(wv[6], wv[7]);

#pragma unroll
    for (int ct = 0; ct < 8; ++ct) {
      const float* xp = xl + (size_t)ct * 16 * N_SZ + t * 32;
      const float4_t x0 = *reinterpret_cast<const float4_t*>(xp);
      const float4_t x1 = *reinterpret_cast<const float4_t*>(xp + 4);
      union { half8_t v; fp16x2_t h[4]; } bb;
      bb.h[0] = __builtin_amdgcn_cvt_pkrtz(x0[0], x0[1]);
      bb.h[1] = __builtin_amdgcn_cvt_pkrtz(x0[2], x0[3]);
      bb.h[2] = __builtin_amdgcn_cvt_pkrtz(x1[0], x1[1]);
      bb.h[3] = __builtin_amdgcn_cvt_pkrtz(x1[2], x1[3]);
      acc[ct] = __builtin_amdgcn_mfma_f32_16x16x32_f16(aa.v, bb.v, acc[ct], 0, 0, 0);
    }
  }

  // 4-wave LDS reduce -> part2[bs][2048]
#pragma unroll
  for (int ct = 0; ct < 8; ++ct)
#pragma unroll
    for (int j = 0; j < 4; ++j)
      red[wid * TILE_F + (q * 4 + j) * C_SZ + ct * 16 + r] = acc[ct][j];
  __syncthreads();

  float* pp = part2 + (size_t)bs * TILE_F;
  for (int i = tid; i < TILE_F; i += THREADS)
    pp[i] = (red[i] + red[TILE_F + i]) + (red[2 * TILE_F + i] + red[3 * TILE_F + i]);
}

// ---------- stage A: fold 16 block tiles -> part3[b][SG][2048], coalesced ------
__global__ __launch_bounds__(THREADS) void kpconv_sumA(
    const float* __restrict__ part2, float* __restrict__ part3) {
  const int sg = blockIdx.x;   // 0..SG-1
  const int b  = blockIdx.y;   // 0..7
  const int tid = threadIdx.x;
  const size_t ebase = (size_t)tid * 8;

  const float* src = part2 + ((size_t)b * S_SPANS + sg * SLOT_PER_SG) * TILE_F + ebase;
  float4_t s0 = {0.f, 0.f, 0.f, 0.f}, s1 = {0.f, 0.f, 0.f, 0.f};
#pragma unroll
  for (int j = 0; j < SLOT_PER_SG; ++j) {
    s0 += *reinterpret_cast<const float4_t*>(src + (size_t)j * TILE_F);
    s1 += *reinterpret_cast<const float4_t*>(src + (size_t)j * TILE_F + 4);
  }
  float* dst = part3 + ((size_t)b * SG + sg) * TILE_F + ebase;
  *reinterpret_cast<float4_t*>(dst)     = s0;
  *reinterpret_cast<float4_t*>(dst + 4) = s1;
}

// ---------- stage B: reduce SG groups + per-k GEMM into out --------------------
__global__ __launch_bounds__(C_SZ) void kpconv_reduce_mf(
    const float* __restrict__ part3, const float* __restrict__ W,
    float* __restrict__ out) {
  const int k = blockIdx.x;    // 0..14 (pad row 15 never read)
  const int b = blockIdx.y;    // 0..7
  const int tid = threadIdx.x; // c
  __shared__ float row[C_SZ];

  const float* pp = part3 + (size_t)b * SG * TILE_F + k * C_SZ + tid;
  float a0 = 0.f, a1 = 0.f;
#pragma unroll
  for (int sg = 0; sg < SG; sg += 2) {
    a0 += pp[(size_t)(sg + 0) * TILE_F];
    a1 += pp[(size_t)(sg + 1) * TILE_F];
  }
  row[tid] = a0 + a1;
  __syncthreads();

  float acc = 0.0f;
  const float* Wk = W + (size_t)k * C_SZ * C_SZ;
#pragma unroll 8
  for (int c = 0; c < C_SZ; ++c) acc = fmaf(row[c], Wk[(size_t)c * C_SZ + tid], acc);
  atomicAdd(&out[b * C_SZ + tid], acc);
}

// ---------- fallback (ws too small): round-12 proven VALU path ----------------
#define FB_ROWS 4
#define FB_G 8
#define FB_NPL 4
#define FB_WSTEP 256
#define FB_NSPAN 2048
#define FB_SPANS 32
#define FB_STEPS 8
#define FB_PART (16 * K_SZ)
#define FB_NBLKS (B_SZ * FB_SPANS * FB_G)

__global__ __launch_bounds__(THREADS, 2) void kpconv_main_fb(
    const float* __restrict__ p, const float* __restrict__ x,
    const float* __restrict__ kp, float* __restrict__ part) {
  __shared__ float kps[K_SZ * 3];
  const int tid = threadIdx.x;
  if (tid < K_SZ * 3) kps[tid] = kp[tid];
  __syncthreads();

  const int blk = blockIdx.x;
  const int cg = blk % FB_G;
  const int bs = blk / FB_G;
  const int b  = bs / FB_SPANS;
  const int s  = bs % FB_SPANS;
  const int lane = tid & 63;
  const int wid  = tid >> 6;

  const float* xl = x + (size_t)b * C_SZ * N_SZ
                  + (size_t)(cg * 16 + wid * FB_ROWS) * N_SZ
                  + s * FB_NSPAN + FB_NPL * lane;
  const float* pb = p + ((size_t)b * N_SZ + s * FB_NSPAN) * 3;

  float acc[FB_ROWS][K_SZ];
#pragma unroll
  for (int r = 0; r < FB_ROWS; ++r)
#pragma unroll
    for (int k = 0; k < K_SZ; ++k) acc[r][k] = 0.0f;

  for (int t = 0; t < FB_STEPS; ++t) {
    float4 xv[FB_ROWS];
#pragma unroll
    for (int r = 0; r < FB_ROWS; ++r)
      xv[r] = *reinterpret_cast<const float4*>(xl + (size_t)r * N_SZ + t * FB_WSTEP);
    const int n0 = t * FB_WSTEP + FB_NPL * lane;
    float w4[4][K_SZ];
#pragma unroll
    for (int j = 0; j < 4; ++j) {
      const float px = pb[3 * (n0 + j) + 0];
      const float py = pb[3 * (n0 + j) + 1];
      const float pz = pb[3 * (n0 + j) + 2];
#pragma unroll
      for (int k = 0; k < K_SZ; ++k) {
        const float dx = px - kps[3 * k + 0];
        const float dy = py - kps[3 * k + 1];
        const float dz = pz - kps[3 * k + 2];
        const float d = sqrtf(fmaf(dx, dx, fmaf(dy, dy, dz * dz)));
        w4[j][k] = fmaxf(1.0f - d * INV_KP_EXTENT, 0.0f);
      }
    }
#pragma unroll
    for (int k = 0; k < K_SZ; ++k)
#pragma unroll
      for (int r = 0; r < FB_ROWS; ++r)
        acc[r][k] = fmaf(w4[0][k], xv[r].x,
                    fmaf(w4[1][k], xv[r].y,
                    fmaf(w4[2][k], xv[r].z,
                    fmaf(w4[3][k], xv[r].w, acc[r][k]))));
  }

  float* pout = part + (size_t)blk * FB_PART + wid * (FB_ROWS * K_SZ);
#pragma unroll
  for (int r = 0; r < FB_ROWS; ++r) {
    float keep = 0.0f;
#pragma unroll
    for (int k = 0; k < K_SZ; ++k) {
      float v = acc[r][k];
      v += __shfl_xor(v, 1);
      v += __shfl_xor(v, 2);
      v += __shfl_xor(v, 4);
      v += __shfl_xor(v, 8);
      v += __shfl_xor(v, 16);
      v += __shfl_xor(v, 32);
      if (lane == k) keep = v;
    }
    if (lane < K_SZ) pout[r * K_SZ + lane] = keep;
  }
}

__global__ __launch_bounds__(C_SZ) void kpconv_reduce_fb(
    const float* __restrict__ part, const float* __restrict__ W,
    float* __restrict__ out) {
  const int k = blockIdx.x;
  const int b = blockIdx.y;
  const int tid = threadIdx.x;
  __shared__ float row[C_SZ];

  const int cg = tid >> 4, wid = (tid >> 2) & 3, r = tid & 3;
  const size_t base = ((size_t)(b * FB_SPANS) * FB_G + cg) * FB_PART
                    + wid * (FB_ROWS * K_SZ) + r * K_SZ + k;
  float sum = 0.0f;
  for (int ss = 0; ss < FB_SPANS; ++ss)
    sum += part[base + (size_t)ss * FB_G * FB_PART];
  row[tid] = sum;
  __syncthreads();

  float acc = 0.0f;
  const float* Wk = W + (size_t)k * C_SZ * C_SZ;
#pragma unroll 8
  for (int c = 0; c < C_SZ; ++c) acc += row[c] * Wk[(size_t)c * C_SZ + tid];
  atomicAdd(&out[b * C_SZ + tid], acc);
}

extern "C" void kernel_launch(void* const* d_in, const int* in_sizes, int n_in,
                              void* d_out, int out_size, void* d_ws, size_t ws_size,
                              hipStream_t stream) {
  const float* p  = (const float*)d_in[0];
  const float* x  = (const float*)d_in[1];
  const float* w  = (const float*)d_in[2];
  const float* kp = (const float*)d_in[3];
  float* out  = (float*)d_out;

  const size_t p2_bytes = (size_t)NBLKS * TILE_F * sizeof(float);        // 8.39 MB
  const size_t p2a = (p2_bytes + 255) & ~(size_t)255;
  const size_t p3_bytes = (size_t)B_SZ * SG * TILE_F * sizeof(float);    // 0.52 MB
  const size_t p3a = (p3_bytes + 255) & ~(size_t)255;

  (void)hipMemsetAsync(d_out, 0, (size_t)out_size * sizeof(float), stream);
  if (ws_size >= p2a + p3a) {
    float* part2 = (float*)d_ws;
    float* part3 = (float*)((char*)d_ws + p2a);
    kpconv_fused<<<dim3(NBLKS), THREADS, 0, stream>>>(p, x, kp, part2);
    kpconv_sumA<<<dim3(SG, B_SZ), THREADS, 0, stream>>>(part2, part3);
    kpconv_reduce_mf<<<dim3(K_SZ, B_SZ), C_SZ, 0, stream>>>(part3, w, out);
  } else {
    float* part = (float*)d_ws;
    kpconv_main_fb<<<dim3(FB_NBLKS), THREADS, 0, stream>>>(p, x, kp, part);
    kpconv_reduce_fb<<<dim3(K_SZ, B_SZ), C_SZ, 0, stream>>>(part, w, out);
  }
}